// Round 6
// baseline (105.858 us; speedup 1.0000x reference)
//
#include <hip/hip_runtime.h>

#define BATCH 8
#define NBOX 4096
#define THRESH 0.8f
#define EPSV 1e-9f
#define BLOCK 256
#define IT 8                        // i-boxes per thread (ILP + LDS amortization)
#define ICH (NBOX / (BLOCK * IT))   // 2 i-chunks per batch
#define JS 32                       // j splits
#define JT (NBOX / JS)              // 128 j per block == one LDS tile

// DET: each (i, jsplit) partial written to its own slot (deterministic, no atomics).
template <bool DET>
__global__ __launch_bounds__(BLOCK) void pair_sum_kernel(
    const float* __restrict__ boxes,   // [B,N,4]
    const int* __restrict__ cls,       // [B,N]
    float* __restrict__ sums)          // DET: [JS,B,N] ; else [B,N]
{
    __shared__ float4 sbox[JT];
    __shared__ float2 sac[JT];  // (area, class bits)

    const int b     = blockIdx.x / ICH;
    const int ich   = blockIdx.x % ICH;
    const int jspl  = blockIdx.y;
    const int jbase = jspl * JT;
    const int tid   = threadIdx.x;

    const float4* bx = reinterpret_cast<const float4*>(boxes) + (size_t)b * NBOX;
    const int* cl = cls + (size_t)b * NBOX;

    // stage j tile (first JT threads)
    if (tid < JT) {
        const int j = jbase + tid;
        float4 bj = bx[j];
        sbox[tid] = bj;
        float aj = (bj.z - bj.x) * (bj.w - bj.y);
        sac[tid] = make_float2(aj, __int_as_float(cl[j]));
    }
    __syncthreads();

    // my i boxes in registers
    float ix1[IT], iy1[IT], ix2[IT], iy2[IT], sum[IT];
    int ic[IT];
    const int ibase = ich * (BLOCK * IT);
#pragma unroll
    for (int t = 0; t < IT; ++t) {
        const int i = ibase + t * BLOCK + tid;
        float4 bi = bx[i];
        ix1[t] = bi.x; iy1[t] = bi.y; ix2[t] = bi.z; iy2[t] = bi.w;
        ic[t] = cl[i];
        sum[t] = 0.0f;
    }

    // inner loop over staged j's (uniform-address LDS reads -> broadcast, no conflicts)
    for (int jj = 0; jj < JT; ++jj) {
        float4 bj = sbox[jj];
        float2 ac = sac[jj];
        int cj = __float_as_int(ac.y);
#pragma unroll
        for (int t = 0; t < IT; ++t) {
            bool ok = (bj.x >= ix1[t]) & (bj.y >= iy1[t]) &
                      (bj.z <= ix2[t]) & (bj.w <= iy2[t]) &
                      (cj == ic[t]);
            sum[t] += ok ? ac.x : 0.0f;   // self (j==i) included; removed in finalize
        }
    }

#pragma unroll
    for (int t = 0; t < IT; ++t) {
        const int i = ibase + t * BLOCK + tid;
        if (DET)
            sums[((size_t)jspl * BATCH + b) * NBOX + i] = sum[t];
        else
            atomicAdd(&sums[(size_t)b * NBOX + i], sum[t]);
    }
}

template <bool DET>
__global__ __launch_bounds__(BLOCK) void finalize_kernel(
    const float* __restrict__ boxes,
    const float* __restrict__ sums,
    float* __restrict__ out)   // [B*N*4] masked boxes, then [B*N] keep
{
    const int idx = blockIdx.x * BLOCK + threadIdx.x;  // over B*N
    float4 bi = reinterpret_cast<const float4*>(boxes)[idx];
    float area = (bi.z - bi.x) * (bi.w - bi.y);
    float s;
    if (DET) {
        s = 0.0f;
#pragma unroll
        for (int p = 0; p < JS; ++p)
            s += sums[(size_t)p * (BATCH * NBOX) + idx];
    } else {
        s = sums[idx];
    }
    s -= area;  // remove self-containment
    float k = (s <= THRESH * (area + EPSV)) ? 1.0f : 0.0f;
    float4 o = make_float4(bi.x * k, bi.y * k, bi.z * k, bi.w * k);
    reinterpret_cast<float4*>(out)[idx] = o;
    out[(size_t)BATCH * NBOX * 4 + idx] = k;
}

extern "C" void kernel_launch(void* const* d_in, const int* in_sizes, int n_in,
                              void* d_out, int out_size, void* d_ws, size_t ws_size,
                              hipStream_t stream) {
    const float* boxes = (const float*)d_in[0];
    const int*   cls   = (const int*)d_in[1];
    float* out  = (float*)d_out;
    float* sums = (float*)d_ws;

    const size_t det_bytes = (size_t)JS * BATCH * NBOX * sizeof(float);  // 4 MiB
    dim3 grid1(BATCH * ICH, JS);

    if (ws_size >= det_bytes) {
        pair_sum_kernel<true><<<grid1, BLOCK, 0, stream>>>(boxes, cls, sums);
        finalize_kernel<true><<<(BATCH * NBOX) / BLOCK, BLOCK, 0, stream>>>(boxes, sums, out);
    } else {
        hipMemsetAsync(sums, 0, (size_t)BATCH * NBOX * sizeof(float), stream);
        pair_sum_kernel<false><<<grid1, BLOCK, 0, stream>>>(boxes, cls, sums);
        finalize_kernel<false><<<(BATCH * NBOX) / BLOCK, BLOCK, 0, stream>>>(boxes, sums, out);
    }
}

// Round 10
// 91.080 us; speedup vs baseline: 1.1623x; 1.1623x over previous
//
#include <hip/hip_runtime.h>

#define BATCH 8
#define NBOX 4096
#define THRESH 0.8f
#define EPSV 1e-9f
#define BLOCK 256
#define IT 4                        // i-boxes per thread
#define ICH (NBOX / (BLOCK * IT))   // 4 i-chunks per batch
#define JS 32                       // j splits (DET ws = 4 MiB, proven to fit)
#define JT (NBOX / JS)              // 128 j per LDS tile

typedef float f32x2 __attribute__((ext_vector_type(2)));

// DET: each (i, jsplit) partial written to its own slot (deterministic, no atomics).
template <bool DET>
__global__ __launch_bounds__(BLOCK, 4) void pair_sum_kernel(
    const float* __restrict__ boxes,   // [B,N,4]
    const int* __restrict__ cls,       // [B,N]
    float* __restrict__ sums)          // DET: [JS,B,N] ; else [B,N]
{
    __shared__ float4 sbox[JT];
    __shared__ float2 sac[JT];  // (class as float, area)

    const int b     = blockIdx.x / ICH;
    const int ich   = blockIdx.x % ICH;
    const int jspl  = blockIdx.y;
    const int jbase = jspl * JT;
    const int tid   = threadIdx.x;

    const float4* bx = reinterpret_cast<const float4*>(boxes) + (size_t)b * NBOX;
    const int* cl = cls + (size_t)b * NBOX;

    // stage j tile (first JT threads)
    if (tid < JT) {
        const int j = jbase + tid;
        float4 bj = bx[j];
        sbox[tid] = bj;
        float aj = (bj.z - bj.x) * (bj.w - bj.y);
        sac[tid] = make_float2((float)cl[j], aj);
    }
    __syncthreads();

    // my i boxes in packed register pairs (enables v_pk_add_f32)
    f32x2 ilo[IT], ihi[IT];
    float ci[IT], sum[IT];
    const int ibase = ich * (BLOCK * IT);
#pragma unroll
    for (int t = 0; t < IT; ++t) {
        const int i = ibase + t * BLOCK + tid;
        float4 bi = bx[i];
        ilo[t] = (f32x2){bi.x, bi.y};
        ihi[t] = (f32x2){bi.z, bi.w};
        ci[t] = (float)cl[i];
        sum[t] = 0.0f;
    }

    // inner loop: arithmetic containment test, no bool materialization.
    // contained(i contains j, same class) <=> m <= 0 where
    // m = max(ix1-jx1, iy1-jy1, jx2-ix2, jy2-iy2, |ci-cj|)
    for (int jj = 0; jj < JT; ++jj) {
        float4 bj = sbox[jj];
        float2 ac = sac[jj];
        f32x2 jlo = (f32x2){bj.x, bj.y};
        f32x2 jhi = (f32x2){bj.z, bj.w};
        float cj = ac.x, aj = ac.y;
#pragma unroll
        for (int t = 0; t < IT; ++t) {
            f32x2 d1 = ilo[t] - jlo;     // v_pk_add_f32 (neg)
            f32x2 d2 = jhi - ihi[t];     // v_pk_add_f32 (neg)
            float dc = ci[t] - cj;
            float m = fmaxf(fmaxf(fmaxf(d1.x, d1.y), d2.x),
                            fmaxf(d2.y, fabsf(dc)));   // v_max3 + v_max(+abs mod)
            sum[t] += (m <= 0.0f) ? aj : 0.0f;         // self (j==i): m==0, removed in finalize
        }
    }

#pragma unroll
    for (int t = 0; t < IT; ++t) {
        const int i = ibase + t * BLOCK + tid;
        if (DET)
            sums[((size_t)jspl * BATCH + b) * NBOX + i] = sum[t];
        else
            atomicAdd(&sums[(size_t)b * NBOX + i], sum[t]);
    }
}

template <bool DET>
__global__ __launch_bounds__(BLOCK) void finalize_kernel(
    const float* __restrict__ boxes,
    const float* __restrict__ sums,
    float* __restrict__ out)   // [B*N*4] masked boxes, then [B*N] keep
{
    const int idx = blockIdx.x * BLOCK + threadIdx.x;  // over B*N
    float4 bi = reinterpret_cast<const float4*>(boxes)[idx];
    float area = (bi.z - bi.x) * (bi.w - bi.y);
    float s;
    if (DET) {
        s = 0.0f;
#pragma unroll
        for (int p = 0; p < JS; ++p)
            s += sums[(size_t)p * (BATCH * NBOX) + idx];
    } else {
        s = sums[idx];
    }
    s -= area;  // remove self-containment
    float k = (s <= THRESH * (area + EPSV)) ? 1.0f : 0.0f;
    float4 o = make_float4(bi.x * k, bi.y * k, bi.z * k, bi.w * k);
    reinterpret_cast<float4*>(out)[idx] = o;
    out[(size_t)BATCH * NBOX * 4 + idx] = k;
}

extern "C" void kernel_launch(void* const* d_in, const int* in_sizes, int n_in,
                              void* d_out, int out_size, void* d_ws, size_t ws_size,
                              hipStream_t stream) {
    const float* boxes = (const float*)d_in[0];
    const int*   cls   = (const int*)d_in[1];
    float* out  = (float*)d_out;
    float* sums = (float*)d_ws;

    const size_t det_bytes = (size_t)JS * BATCH * NBOX * sizeof(float);  // 4 MiB
    dim3 grid1(BATCH * ICH, JS);   // 1024 blocks = 4/CU

    if (ws_size >= det_bytes) {
        pair_sum_kernel<true><<<grid1, BLOCK, 0, stream>>>(boxes, cls, sums);
        finalize_kernel<true><<<(BATCH * NBOX) / BLOCK, BLOCK, 0, stream>>>(boxes, sums, out);
    } else {
        hipMemsetAsync(sums, 0, (size_t)BATCH * NBOX * sizeof(float), stream);
        pair_sum_kernel<false><<<grid1, BLOCK, 0, stream>>>(boxes, cls, sums);
        finalize_kernel<false><<<(BATCH * NBOX) / BLOCK, BLOCK, 0, stream>>>(boxes, sums, out);
    }
}

// Round 12
// 83.373 us; speedup vs baseline: 1.2697x; 1.0924x over previous
//
#include <hip/hip_runtime.h>

#define BATCH 8
#define NBOX 4096
#define NCLS 80
#define THRESH 0.8f
#define EPSV 1e-9f

#define HS_THREADS 256
#define CHUNK (NBOX / HS_THREADS)   // 16 elements per thread (stable within chunk)

// One block per batch: class histogram -> stable counting sort by class.
// Deterministic ranks: rank = classOffset + chunkPrefix[chunk][c] + withinChunkOrder.
__global__ __launch_bounds__(HS_THREADS) void hist_sort_kernel(
    const float* __restrict__ boxes, const int* __restrict__ cls,
    float4* __restrict__ sBox, float* __restrict__ sArea,
    int* __restrict__ inv, int* __restrict__ segStart, int* __restrict__ segLen)
{
    __shared__ unsigned char  cnt[HS_THREADS][NCLS];   // 20480 B (CHUNK<=255 fits u8)
    __shared__ unsigned short pre[HS_THREADS][NCLS];   // 40960 B
    __shared__ int offs[NCLS];
    __shared__ int tot[NCLS];

    const int b = blockIdx.x, tid = threadIdx.x;
    const int* cl = cls + b * NBOX;
    const float4* bx = reinterpret_cast<const float4*>(boxes) + (size_t)b * NBOX;

    for (int c = 0; c < NCLS; ++c) cnt[tid][c] = 0;   // own row, no race
    const int base = tid * CHUNK;
    int myc[CHUNK];
    for (int k = 0; k < CHUNK; ++k) { int c = cl[base + k]; myc[k] = c; cnt[tid][c]++; }
    __syncthreads();

    if (tid < NCLS) {  // per-class prefix over chunks
        int run = 0;
        for (int ch = 0; ch < HS_THREADS; ++ch) {
            pre[ch][tid] = (unsigned short)run;
            run += cnt[ch][tid];
        }
        tot[tid] = run;
    }
    __syncthreads();
    if (tid == 0) { int r = 0; for (int c = 0; c < NCLS; ++c) { offs[c] = r; r += tot[c]; } }
    __syncthreads();
    if (tid < NCLS) { segStart[b * NCLS + tid] = offs[tid]; segLen[b * NCLS + tid] = tot[tid]; }

    for (int c = 0; c < NCLS; ++c) cnt[tid][c] = 0;   // reuse as running counter (own row)
    for (int k = 0; k < CHUNK; ++k) {
        int c = myc[k];
        int rank = offs[c] + (int)pre[tid][c] + (int)(cnt[tid][c]++);
        float4 bb = bx[base + k];
        sBox[(size_t)b * NBOX + rank] = bb;
        sArea[(size_t)b * NBOX + rank] = (bb.z - bb.x) * (bb.w - bb.y);
        inv[(size_t)b * NBOX + base + k] = rank;
    }
}

#define PT 64
#define JTILE 512

// One wave per (batch, class): all-pairs within the class segment.
__global__ __launch_bounds__(PT) void class_pairs_kernel(
    const float4* __restrict__ sBox, const float* __restrict__ sArea,
    const int* __restrict__ segStart, const int* __restrict__ segLen,
    float* __restrict__ sums)
{
    const int b = blockIdx.x / NCLS, c = blockIdx.x % NCLS;
    const int s0 = segStart[b * NCLS + c], len = segLen[b * NCLS + c];
    if (len == 0) return;

    __shared__ float4 jb[JTILE];
    __shared__ float  ja[JTILE];
    const int lane = threadIdx.x;
    const float4* BB = sBox + (size_t)b * NBOX + s0;
    const float*  AA = sArea + (size_t)b * NBOX + s0;

    for (int ib = 0; ib < len; ib += PT) {
        const int ir = ib + lane;
        const bool act = ir < len;
        float4 bi = act ? BB[ir] : make_float4(2.f, 2.f, -1.f, -1.f);  // contains nothing
        float sum = 0.f;
        for (int jt = 0; jt < len; jt += JTILE) {
            const int n = min(JTILE, len - jt);
            __syncthreads();
            for (int k = lane; k < n; k += PT) { jb[k] = BB[jt + k]; ja[k] = AA[jt + k]; }
            __syncthreads();
            for (int k = 0; k < n; ++k) {     // ascending rank = ascending orig idx
                float4 bj = jb[k];
                float m = fmaxf(fmaxf(bi.x - bj.x, bi.y - bj.y),
                                fmaxf(bj.z - bi.z, bj.w - bi.w));
                sum += (m <= 0.f) ? ja[k] : 0.f;   // self included; removed in finalize
            }
        }
        if (act) sums[(size_t)b * NBOX + s0 + ir] = sum;
    }
}

__global__ __launch_bounds__(256) void finalize_kernel(
    const float* __restrict__ boxes, const float* __restrict__ sums,
    const int* __restrict__ inv, float* __restrict__ out)
{
    const int idx = blockIdx.x * 256 + threadIdx.x;  // over B*N
    const int b = idx >> 12;                          // N = 4096
    float4 bi = reinterpret_cast<const float4*>(boxes)[idx];
    float area = (bi.z - bi.x) * (bi.w - bi.y);
    float s = sums[(size_t)b * NBOX + inv[idx]] - area;  // remove self-containment
    float k = (s <= THRESH * (area + EPSV)) ? 1.f : 0.f;
    reinterpret_cast<float4*>(out)[idx] = make_float4(bi.x * k, bi.y * k, bi.z * k, bi.w * k);
    out[(size_t)BATCH * NBOX * 4 + idx] = k;
}

extern "C" void kernel_launch(void* const* d_in, const int* in_sizes, int n_in,
                              void* d_out, int out_size, void* d_ws, size_t ws_size,
                              hipStream_t stream) {
    const float* boxes = (const float*)d_in[0];
    const int*   cls   = (const int*)d_in[1];
    float* out = (float*)d_out;

    // workspace layout (~1.2 MiB, ws is far larger)
    char* w = (char*)d_ws;
    float4* sBox    = (float4*)(w);                                   // 512 KiB
    float*  sArea   = (float*)(w + (size_t)BATCH * NBOX * 16);        // 128 KiB
    int*    inv     = (int*)(w + (size_t)BATCH * NBOX * 20);          // 128 KiB
    float*  sums    = (float*)(w + (size_t)BATCH * NBOX * 24);        // 128 KiB
    int*    segSt   = (int*)(w + (size_t)BATCH * NBOX * 28);          // 2.5 KiB
    int*    segLn   = (int*)(w + (size_t)BATCH * NBOX * 28 + BATCH * NCLS * 4);

    hist_sort_kernel<<<BATCH, HS_THREADS, 0, stream>>>(boxes, cls, sBox, sArea, inv, segSt, segLn);
    class_pairs_kernel<<<BATCH * NCLS, PT, 0, stream>>>(sBox, sArea, segSt, segLn, sums);
    finalize_kernel<<<(BATCH * NBOX) / 256, 256, 0, stream>>>(boxes, sums, inv, out);
}